// Round 23
// baseline (150.895 us; speedup 1.0000x reference)
//
#include <hip/hip_runtime.h>
#include <hip/hip_bf16.h>
#include <math.h>

// Problem constants (B=4, T=2048, C=1024, H=16, HS=64)
#define BB 4
#define TT 2048
#define CC 1024
#define HH 16
#define HS 64
#define ROWS (BB*TT)          // 8192

typedef __bf16 bf16_t;
typedef __bf16 bf16x8 __attribute__((ext_vector_type(8)));
typedef __bf16 bf16x4v __attribute__((ext_vector_type(4)));
typedef __bf16 bf16x2 __attribute__((ext_vector_type(2)));
typedef float  f32x4  __attribute__((ext_vector_type(4)));
typedef float  f32x16 __attribute__((ext_vector_type(16)));
typedef unsigned u32x4 __attribute__((ext_vector_type(4)));

// async global->LDS, 16B per lane; LDS dest is wave-uniform base + lane*16
#define GLDS16(g, l) __builtin_amdgcn_global_load_lds( \
    (const __attribute__((address_space(1))) void*)(g), \
    (__attribute__((address_space(3))) void*)(l), 16, 0, 0)

#define KSCALE 0.04508422002778011f   /* (1/32) * log2(e), folded into u */
#define LOG2E  1.4426950408889634f

// raw HW exp2: single v_exp_f32 (args here are bounded; no denorm fixup needed)
#define EXP2R(x) __builtin_amdgcn_exp2f(x)

// ---------------------------------------------------------------------------
// Fused prep kernel: blocks 0..4095 = fp32->bf16 convert of x;
// 4096..4863 = 3x weight transpose+convert; 4864 = W1/W2 transpose.
// ---------------------------------------------------------------------------
__global__ __launch_bounds__(256) void prep_kernel(
    const float* __restrict__ x, bf16_t* __restrict__ xbf,
    const float* __restrict__ Wu, const float* __restrict__ Wv,
    const float* __restrict__ Wp,
    bf16_t* __restrict__ WuT, bf16_t* __restrict__ WvT, bf16_t* __restrict__ WpT,
    const float* __restrict__ W1, const float* __restrict__ W2,
    bf16_t* __restrict__ W1T, bf16_t* __restrict__ W2T)
{
    const int bid = blockIdx.x;
    const int tid = threadIdx.x;
    if (bid < 4096) {
        const size_t i = ((size_t)bid * 256 + tid) * 8;
        const float4 a = *reinterpret_cast<const float4*>(&x[i]);
        const float4 b = *reinterpret_cast<const float4*>(&x[i + 4]);
        bf16x8 o;
        o[0] = (bf16_t)a.x; o[1] = (bf16_t)a.y; o[2] = (bf16_t)a.z; o[3] = (bf16_t)a.w;
        o[4] = (bf16_t)b.x; o[5] = (bf16_t)b.y; o[6] = (bf16_t)b.z; o[7] = (bf16_t)b.w;
        *reinterpret_cast<bf16x8*>(&xbf[i]) = o;
    } else if (bid < 4864) {
        __shared__ float t[64][65];
        const int local = bid - 4096;
        const int m = local >> 8;
        const float* W = (m == 0) ? Wu : (m == 1) ? Wv : Wp;
        bf16_t* Wt = (m == 0) ? WuT : (m == 1) ? WvT : WpT;
        const int r0 = ((local >> 4) & 15) * 64, c0 = (local & 15) * 64;
        #pragma unroll
        for (int l = 0; l < 16; ++l) {
            int idx = tid + l * 256;
            int rr = idx >> 6, cc = idx & 63;
            t[rr][cc] = W[(size_t)(r0 + rr) * CC + c0 + cc];
        }
        __syncthreads();
        #pragma unroll
        for (int l = 0; l < 16; ++l) {
            int idx = tid + l * 256;
            int rr = idx >> 6, cc = idx & 63;
            Wt[(size_t)(c0 + rr) * CC + r0 + cc] = (bf16_t)t[cc][rr];
        }
    } else {
        __shared__ float t1[64][65], t2[64][65];
        #pragma unroll
        for (int l = 0; l < 16; ++l) {
            int idx = tid + l * 256;
            int rr = idx >> 6, cc = idx & 63;
            t1[rr][cc] = W1[idx]; t2[rr][cc] = W2[idx];
        }
        __syncthreads();
        #pragma unroll
        for (int l = 0; l < 16; ++l) {
            int idx = tid + l * 256;
            int rr = idx >> 6, cc = idx & 63;
            W1T[idx] = (bf16_t)t1[cc][rr];
            W2T[idx] = (bf16_t)t2[cc][rr];
        }
    }
}

// ---------------------------------------------------------------------------
// 256x256 8-phase uv GEMM (T3+T4+T5 + T1 XCD swizzle):
//   [u|v] = A @ [WuT||WvT]^T + [bu|bv].
// ---------------------------------------------------------------------------
__global__ __launch_bounds__(512, 2) void mfma_gemm_uv8_kernel(
    const bf16_t* __restrict__ A, const bf16_t* __restrict__ Bt,
    const float* __restrict__ bu, const float* __restrict__ bv,
    bf16_t* __restrict__ uout, bf16_t* __restrict__ vout)
{
    __shared__ __align__(16) char smem[131072];   // [buf][A 32K | B 32K]
    const int tid = threadIdx.x;
    const int wave = tid >> 6, lane = tid & 63;
    const int bid = (int)blockIdx.x;              // 0..255
    const int xcd = bid & 7, lid = bid >> 3;      // 32 blocks per XCD
    const int xq = (xcd & 1) * 4 + (lid & 3);     // col-block 0..7
    const int yq = (xcd >> 1) * 8 + (lid >> 2);   // row-block 0..31
    const int row0 = yq * 256, col0 = xq * 256;
    const int wm = wave >> 2, wn = wave & 3;      // 2 x 4 wave grid
    const int lr = lane & 15, ko = lane >> 4;
    const int koff = ((lane & 7) ^ (lane >> 3)) << 3;   // staging inverse swz
    const int rsub = lane >> 3;

    int rdc[2];
    #pragma unroll
    for (int ks = 0; ks < 2; ++ks)
        rdc[ks] = ((((ks << 2) + ko) ^ (lr & 7)) << 4);
    const int arow = (wm << 7) + lr;
    const int brow = (wn << 6) + lr;

    f32x4 acc[8][4];
    #pragma unroll
    for (int i = 0; i < 8; ++i)
        #pragma unroll
        for (int j = 0; j < 4; ++j) acc[i][j] = (f32x4){0.f, 0.f, 0.f, 0.f};

    auto stageA = [&](int t, int bufbase) {       // 4 A loads per wave
        const int k0 = t << 6;
        const bf16_t* ag = A + (size_t)(row0 + wave * 8 + rsub) * CC + k0 + koff;
        char* da = smem + bufbase + wave * 1024;
        #pragma unroll
        for (int a = 0; a < 4; ++a) {
            GLDS16(ag, da);
            ag += 64 * CC; da += 8192;
        }
    };
    auto stageB = [&](int t, int bufbase) {       // 4 B loads per wave
        const int k0 = t << 6;
        const bf16_t* bg = Bt + (size_t)(col0 + wave * 8 + rsub) * CC + k0 + koff;
        char* db = smem + bufbase + 32768 + wave * 1024;
        #pragma unroll
        for (int a = 0; a < 4; ++a) {
            GLDS16(bg, db);
            bg += 64 * CC; db += 8192;
        }
    };

    bf16x8 bfr[4][2];
    auto phase = [&](int bufbase, int mi0, bool withB) {
        const char* sA = smem + bufbase;
        const char* sB = smem + bufbase + 32768;
        if (withB) {
            #pragma unroll
            for (int ni = 0; ni < 4; ++ni)
                #pragma unroll
                for (int ks = 0; ks < 2; ++ks)
                    bfr[ni][ks] = *reinterpret_cast<const bf16x8*>(
                        sB + (brow + ni * 16) * 128 + rdc[ks]);
        }
        bf16x8 af[2][2];
        #pragma unroll
        for (int m2 = 0; m2 < 2; ++m2)
            #pragma unroll
            for (int ks = 0; ks < 2; ++ks)
                af[m2][ks] = *reinterpret_cast<const bf16x8*>(
                    sA + (arow + (mi0 + m2) * 16) * 128 + rdc[ks]);
        __builtin_amdgcn_s_setprio(1);
        #pragma unroll
        for (int m2 = 0; m2 < 2; ++m2)
            #pragma unroll
            for (int ni = 0; ni < 4; ++ni)
                #pragma unroll
                for (int ks = 0; ks < 2; ++ks)
                    acc[mi0 + m2][ni] = __builtin_amdgcn_mfma_f32_16x16x32_bf16(
                        af[m2][ks], bfr[ni][ks], acc[mi0 + m2][ni], 0, 0, 0);
        __builtin_amdgcn_s_setprio(0);
        asm volatile("s_barrier" ::: "memory");
    };

    stageA(0, 0);     stageB(0, 0);
    stageA(1, 65536); stageB(1, 65536);
    asm volatile("s_waitcnt vmcnt(8)" ::: "memory");
    asm volatile("s_barrier" ::: "memory");

    for (int i = 0; i < 8; ++i) {
        const int t0 = 2 * i;
        phase(0, 0, true);
        if (t0 + 2 < 16) stageB(t0 + 2, 0);          // B region dead after ph1
        phase(0, 2, false); phase(0, 4, false); phase(0, 6, false);
        if (t0 + 2 < 16) {
            stageA(t0 + 2, 0);
            asm volatile("s_waitcnt vmcnt(8)" ::: "memory");   // t0+1 ready
        } else {
            asm volatile("s_waitcnt vmcnt(0)" ::: "memory");
        }
        asm volatile("s_barrier" ::: "memory");
        phase(65536, 0, true);
        if (t0 + 3 < 16) stageB(t0 + 3, 65536);
        phase(65536, 2, false); phase(65536, 4, false); phase(65536, 6, false);
        if (t0 + 3 < 16) {
            stageA(t0 + 3, 65536);
            asm volatile("s_waitcnt vmcnt(8)" ::: "memory");   // t0+2 ready
            asm volatile("s_barrier" ::: "memory");
        }
    }

    const bool isU = (col0 < 1024);
    const float* const bias = isU ? bu : bv;
    const float scl = isU ? KSCALE : 1.0f;
    bf16_t* const outp = isU ? uout : vout;
    const int cbase = col0 & 1023;

    float bv4[4];
    #pragma unroll
    for (int ni = 0; ni < 4; ++ni)
        bv4[ni] = bias[cbase + wn * 64 + ni * 16 + lr];
    #pragma unroll
    for (int mi = 0; mi < 8; ++mi)
        #pragma unroll
        for (int j = 0; j < 4; ++j) {
            const int grow = row0 + wm * 128 + mi * 16 + ko * 4 + j;
            #pragma unroll
            for (int ni = 0; ni < 4; ++ni) {
                const int gcol = cbase + wn * 64 + ni * 16 + lr;
                outp[(size_t)grow * CC + gcol] =
                    (bf16_t)((acc[mi][ni][j] + bv4[ni]) * scl);
            }
        }
}

// ---------------------------------------------------------------------------
// 256x128 8-phase out GEMM (+ T1 XCD swizzle): out = ybf @ WpT + bp (fp32)
// ---------------------------------------------------------------------------
__global__ __launch_bounds__(512, 1) void mfma_gemm_out8_kernel(
    const bf16_t* __restrict__ A, const bf16_t* __restrict__ Bt,
    const float* __restrict__ bias, float* __restrict__ Cout)
{
    __shared__ __align__(16) char smem[98304];    // buf b at b*49152: A 32K, B 16K
    const int tid = threadIdx.x;
    const int wave = tid >> 6, lane = tid & 63;
    const int bid = (int)blockIdx.x;              // 0..255
    const int xcd = bid & 7, lid = bid >> 3;
    const int xq = (xcd & 1) * 4 + (lid & 3);     // col-block 0..7
    const int yq = (xcd >> 1) * 8 + (lid >> 2);   // row-block 0..31
    const int row0 = yq * 256, col0 = xq * 128;
    const int wm = wave >> 2, wn = wave & 3;
    const int lr = lane & 15, ko = lane >> 4;
    const int koff = ((lane & 7) ^ (lane >> 3)) << 3;
    const int rsub = lane >> 3;

    int rdc[2];
    #pragma unroll
    for (int ks = 0; ks < 2; ++ks)
        rdc[ks] = ((((ks << 2) + ko) ^ (lr & 7)) << 4);
    const int arow = (wm << 7) + lr;
    const int brow = (wn << 5) + lr;

    f32x4 acc[8][2];
    #pragma unroll
    for (int i = 0; i < 8; ++i)
        #pragma unroll
        for (int j = 0; j < 2; ++j) acc[i][j] = (f32x4){0.f, 0.f, 0.f, 0.f};

    auto stage = [&](int t, int bufbase) {
        const int k0 = t << 6;
        const bf16_t* ag = A + (size_t)(row0 + wave * 8 + rsub) * CC + k0 + koff;
        char* da = smem + bufbase + wave * 1024;
        #pragma unroll
        for (int a = 0; a < 4; ++a) {
            GLDS16(ag, da);
            ag += 64 * CC; da += 8192;
        }
        const bf16_t* bg = Bt + (size_t)(col0 + wave * 8 + rsub) * CC + k0 + koff;
        char* db = smem + bufbase + 32768 + wave * 1024;
        GLDS16(bg, db);
        GLDS16(bg + (size_t)64 * CC, db + 8192);
    };

    bf16x8 bfr[2][2];
    auto phase = [&](int bufbase, int mi0, bool withB) {
        const char* sA = smem + bufbase;
        const char* sB = smem + bufbase + 32768;
        if (withB) {
            #pragma unroll
            for (int ni = 0; ni < 2; ++ni)
                #pragma unroll
                for (int ks = 0; ks < 2; ++ks)
                    bfr[ni][ks] = *reinterpret_cast<const bf16x8*>(
                        sB + (brow + ni * 16) * 128 + rdc[ks]);
        }
        bf16x8 af[2][2];
        #pragma unroll
        for (int m2 = 0; m2 < 2; ++m2)
            #pragma unroll
            for (int ks = 0; ks < 2; ++ks)
                af[m2][ks] = *reinterpret_cast<const bf16x8*>(
                    sA + (arow + (mi0 + m2) * 16) * 128 + rdc[ks]);
        __builtin_amdgcn_s_setprio(1);
        #pragma unroll
        for (int m2 = 0; m2 < 2; ++m2)
            #pragma unroll
            for (int ni = 0; ni < 2; ++ni)
                #pragma unroll
                for (int ks = 0; ks < 2; ++ks)
                    acc[mi0 + m2][ni] = __builtin_amdgcn_mfma_f32_16x16x32_bf16(
                        af[m2][ks], bfr[ni][ks], acc[mi0 + m2][ni], 0, 0, 0);
        __builtin_amdgcn_s_setprio(0);
        asm volatile("s_barrier" ::: "memory");
    };

    stage(0, 0);
    stage(1, 49152);
    asm volatile("s_waitcnt vmcnt(6)" ::: "memory");
    asm volatile("s_barrier" ::: "memory");

    for (int i = 0; i < 8; ++i) {
        const int t0 = 2 * i;
        phase(0, 0, true); phase(0, 2, false); phase(0, 4, false); phase(0, 6, false);
        if (t0 + 2 < 16) {
            stage(t0 + 2, 0);
            asm volatile("s_waitcnt vmcnt(6)" ::: "memory");
        } else {
            asm volatile("s_waitcnt vmcnt(0)" ::: "memory");
        }
        asm volatile("s_barrier" ::: "memory");
        phase(49152, 0, true); phase(49152, 2, false);
        phase(49152, 4, false); phase(49152, 6, false);
        if (t0 + 3 < 16) {
            stage(t0 + 3, 49152);
            asm volatile("s_waitcnt vmcnt(6)" ::: "memory");
            asm volatile("s_barrier" ::: "memory");
        }
    }

    float bv2[2];
    #pragma unroll
    for (int ni = 0; ni < 2; ++ni)
        bv2[ni] = bias[col0 + wn * 32 + ni * 16 + lr];
    #pragma unroll
    for (int mi = 0; mi < 8; ++mi)
        #pragma unroll
        for (int j = 0; j < 4; ++j) {
            const int grow = row0 + wm * 128 + mi * 16 + ko * 4 + j;
            #pragma unroll
            for (int ni = 0; ni < 2; ++ni) {
                const int gcol = col0 + wn * 32 + ni * 16 + lr;
                Cout[(size_t)grow * CC + gcol] = acc[mi][ni][j] + bv2[ni];
            }
        }
}

// ---------------------------------------------------------------------------
// MFMA gated transform, transposed output -> vbT [B*H][64][TT] (kappa cols).
// ---------------------------------------------------------------------------
__global__ __launch_bounds__(256) void gate_mfma_kernel(
    const bf16_t* __restrict__ vp,
    const bf16_t* __restrict__ W1T, const bf16_t* __restrict__ W2T,
    const float* __restrict__ b1, const float* __restrict__ b2,
    bf16_t* __restrict__ vbT)
{
    __shared__ __align__(16) bf16_t Vs[64][64];
    const int tid = threadIdx.x, wave = tid >> 6, lane = tid & 63;
    const int t0 = blockIdx.x * 64;
    const int h = blockIdx.y;
    const int lr = lane & 15, ko = lane >> 4;
    const int koff = ((lane & 7) ^ (lane >> 3)) << 3;
    const int rsub = lane >> 3;

    #pragma unroll
    for (int i = 0; i < 2; ++i) {
        const int rb = (wave * 2 + i) * 8;
        GLDS16(vp + (size_t)(t0 + rb + rsub) * CC + h * 64 + koff,
               (char*)&Vs[rb][0]);
    }
    asm volatile("s_waitcnt vmcnt(0)" ::: "memory");
    __syncthreads();

    bf16x8 w1f[4][2], w2f[4][2];
    #pragma unroll
    for (int ni = 0; ni < 4; ++ni)
        #pragma unroll
        for (int kc = 0; kc < 2; ++kc) {
            w1f[ni][kc] = *reinterpret_cast<const bf16x8*>(
                &W1T[(ni * 16 + lr) * 64 + kc * 32 + ko * 8]);
            w2f[ni][kc] = *reinterpret_cast<const bf16x8*>(
                &W2T[(ni * 16 + lr) * 64 + kc * 32 + ko * 8]);
        }
    const int trow = wave * 16 + lr;
    bf16x8 vf[2];
    #pragma unroll
    for (int kc = 0; kc < 2; ++kc)
        vf[kc] = *reinterpret_cast<const bf16x8*>(
            (char*)Vs + trow * 128 + ((((kc << 2) + ko) ^ (trow & 7)) << 4));

    f32x4 Aacc[4], Gacc[4];
    #pragma unroll
    for (int ni = 0; ni < 4; ++ni) {
        Aacc[ni] = (f32x4){0.f, 0.f, 0.f, 0.f};
        Gacc[ni] = (f32x4){0.f, 0.f, 0.f, 0.f};
    }
    #pragma unroll
    for (int ni = 0; ni < 4; ++ni)
        #pragma unroll
        for (int kc = 0; kc < 2; ++kc) {
            Aacc[ni] = __builtin_amdgcn_mfma_f32_16x16x32_bf16(
                w1f[ni][kc], vf[kc], Aacc[ni], 0, 0, 0);
            Gacc[ni] = __builtin_amdgcn_mfma_f32_16x16x32_bf16(
                w2f[ni][kc], vf[kc], Gacc[ni], 0, 0, 0);
        }

    const int bidx = t0 >> 11;
    const int q2 = (lr >> 2) & 3;
    const int lrk = lr + (q2 == 1 ? 4 : (q2 == 2 ? -4 : 0));
    const int tb = (t0 & 2047) + wave * 16 + lrk;
    const size_t obase = (size_t)(bidx * HH + h) * HS * TT;
    #pragma unroll
    for (int ni = 0; ni < 4; ++ni)
        #pragma unroll
        for (int j = 0; j < 4; ++j) {
            const int d = ni * 16 + ko * 4 + j;
            const float vterm = (float)*(const bf16_t*)(
                (const char*)Vs + trow * 128 +
                ((((d >> 3) ^ (trow & 7)) << 4) + (d & 7) * 2));
            const float a = Aacc[ni][j] + b1[d];
            const float g = Gacc[ni][j] + b2[d];
            const float val = (vterm + a) * (1.f / (1.f + EXP2R(-g * LOG2E)));
            vbT[obase + (size_t)d * TT + tb] = (bf16_t)val;
        }
}

// ---------------------------------------------------------------------------
// MFMA flash attention v18: = v17 with the two 64-key sub-tiles of each
// 128-key trip explicitly interleaved (QK0; QK1; SM+PV0; SM+PV1) so the
// MFMA pipe sees 4 independent chains and sub-1's QK overlaps sub-0's
// softmax VALU. Math/barriers/staging identical to v17.
// ---------------------------------------------------------------------------
__global__ __launch_bounds__(512) void attn_mfma18_kernel(
    const bf16_t* __restrict__ ubf, const bf16_t* __restrict__ xbf,
    const bf16_t* __restrict__ vbT, bf16_t* __restrict__ ybf)
{
    __shared__ __align__(16) char KV[2 * 32768];   // buf b at b*32768: K 16K, V 16K

    const int tid = threadIdx.x, wave = tid >> 6, lane = tid & 63;
    const int l31 = lane & 31, hi = lane >> 5;
    const int koff = ((lane & 7) ^ (lane >> 3)) << 3;   // K staging inverse swz
    const int rsub = lane >> 3;

    // static balanced work mapping (18 trips/CU, heavy first)
    const int w = (int)blockIdx.x;          // 0..511
    const int s = w >> 8;                   // start order 0/1
    const int m = (w >> 6) & 3;
    const int qg = s ? m : 7 - m;           // pairs {m, 7-m}
    const int h = w & 15, b = (w >> 4) & 3;

    int lak[4], lav[4];
    #pragma unroll
    for (int cc = 0; cc < 4; ++cc) {
        const int xr = ((2 * cc + hi) ^ (l31 & 7)) << 4;
        lak[cc] = l31 * 128 + xr;
        lav[cc] = l31 * 256 + xr;
    }
    const int voffA = (((lane & 15) ^ (lane >> 4)) << 3);
    const int voffB = (((lane & 15) ^ ((lane >> 4) + 4)) << 3);

    const int q0w = qg * 256 + wave * 32;
    const size_t rbase = (size_t)b * TT;
    const int hcol = h * 64;
    const size_t hVT = (size_t)(b * HH + h) * HS * TT;

    bf16x8 qf[4];
    #pragma unroll
    for (int dk = 0; dk < 4; ++dk)
        qf[dk] = *reinterpret_cast<const bf16x8*>(
            &ubf[(rbase + q0w + l31) * CC + hcol + dk * 16 + hi * 8]);

    f32x16 O[2];
    #pragma unroll
    for (int dt = 0; dt < 2; ++dt)
        #pragma unroll
        for (int r = 0; r < 16; ++r) O[dt][r] = 0.f;
    float l_ = 0.f;

    const int myn64 = (q0w + 95) >> 6;      // 64-key tiles needed
    const int mx128 = 2 * qg + 2;           // 128-key trips (>= 2)

    const bf16_t* xsK = xbf + (rbase + wave * 16 + rsub) * CC + hcol + koff;
    const bf16_t* vsA = vbT + hVT + (size_t)(wave * 8 + (lane >> 4)) * TT + voffA;
    const bf16_t* vsB = vbT + hVT + (size_t)(wave * 8 + (lane >> 4)) * TT + voffB;

    auto stage = [&](int bufbase) {         // 4 GLDS16 calls per wave
        char* dK = KV + bufbase + wave * 2048;          // K rows wave*16..+16
        GLDS16(xsK,          dK);
        GLDS16(xsK + 8 * CC, dK + 1024);
        char* dV = KV + bufbase + 16384 + wave * 2048;  // V rows wave*8..+8
        GLDS16(vsA,          dV);
        GLDS16(vsB + 4 * TT, dV + 1024);
        xsK += 128 * CC; vsA += 128; vsB += 128;
    };

    // QK^T for one 64-key sub-tile: S[kb] = K @ U'^T (col=query, row=key)
    auto qk = [&](const char* base, int ss, f32x16* S) {
        __builtin_amdgcn_s_setprio(1);
        #pragma unroll
        for (int kb = 0; kb < 2; ++kb) {
            f32x16 z;
            #pragma unroll
            for (int r = 0; r < 16; ++r) z[r] = 0.f;
            f32x16 sv = __builtin_amdgcn_mfma_f32_32x32x16_bf16(
                *reinterpret_cast<const bf16x8*>(
                    base + ss * 8192 + kb * 4096 + lak[0]),
                qf[0], z, 0, 0, 0);
            #pragma unroll
            for (int dk = 1; dk < 4; ++dk)
                sv = __builtin_amdgcn_mfma_f32_32x32x16_bf16(
                    *reinterpret_cast<const bf16x8*>(
                        base + ss * 8192 + kb * 4096 + lak[dk]),
                    qf[dk], sv, 0, 0, 0);
            S[kb] = sv;
        }
        __builtin_amdgcn_s_setprio(0);
    };

    // mask (diag only) + softmax + PV for one sub-tile
    auto smpv = [&](const char* base, int ss, int j, f32x16* S) {
        if (j == myn64 - 1) {
            const int k0 = j * 64;
            const int q = q0w + l31;
            #pragma unroll
            for (int kb = 0; kb < 2; ++kb)
                #pragma unroll
                for (int r = 0; r < 16; ++r) {
                    const int key = k0 + kb * 32 + (r & 3) + 8 * (r >> 2) + 4 * hi;
                    if (key > q) S[kb][r] = -1e30f;
                }
        }

        unsigned pw[2][4][2];
        float ps0 = 0.f, ps1 = 0.f;
        #pragma unroll
        for (int kb = 0; kb < 2; ++kb)
            #pragma unroll
            for (int gq = 0; gq < 4; ++gq)
                #pragma unroll
                for (int jj = 0; jj < 2; ++jj) {
                    const float p0 = EXP2R(S[kb][4 * gq + 2 * jj + 0]);
                    const float p1 = EXP2R(S[kb][4 * gq + 2 * jj + 1]);
                    ps0 += p0; ps1 += p1;
                    bf16x2 t; t[0] = (bf16_t)p0; t[1] = (bf16_t)p1;
                    pw[kb][gq][jj] = __builtin_bit_cast(unsigned, t);
                }
        l_ += ps0 + ps1;

        bf16x8 pfr[2][2];
        #pragma unroll
        for (int kb = 0; kb < 2; ++kb)
            #pragma unroll
            for (int ks = 0; ks < 2; ++ks) {
                u32x4 fw = {pw[kb][2 * ks][0], pw[kb][2 * ks][1],
                            pw[kb][2 * ks + 1][0], pw[kb][2 * ks + 1][1]};
                pfr[kb][ks] = __builtin_bit_cast(bf16x8, fw);
            }

        __builtin_amdgcn_s_setprio(1);
        #pragma unroll
        for (int dt = 0; dt < 2; ++dt)
            #pragma unroll
            for (int kb = 0; kb < 2; ++kb)
                #pragma unroll
                for (int ks = 0; ks < 2; ++ks) {
                    const bf16x8 vt = *reinterpret_cast<const bf16x8*>(
                        base + 16384 + dt * 8192 + ss * 128 + lav[2 * kb + ks]);
                    O[dt] = __builtin_amdgcn_mfma_f32_32x32x16_bf16(
                        vt, pfr[kb][ks], O[dt], 0, 0, 0);
                }
        __builtin_amdgcn_s_setprio(0);
    };

    // prologue: stage trips 0 (buf0) and 1 (buf1; mx128 >= 2 always)
    stage(0);
    stage(32768);
    asm volatile("s_waitcnt vmcnt(4)" ::: "memory");   // qf + trip0 done
    asm volatile("s_barrier" ::: "memory");

    int boff = 0;
    for (int kt = 0; kt < mx128; ++kt) {
        const int j0 = 2 * kt;
        const char* const base = KV + boff;
        const bool has0 = (j0 < myn64);
        const bool has1 = (j0 + 1 < myn64);
        f32x16 S0[2], S1[2];
        // both QK phases first: 4 independent MFMA chains in flight;
        // sub-1 QK overlaps sub-0 softmax (different pipes)
        if (has0) qk(base, 0, S0);
        if (has1) qk(base, 1, S1);
        if (has0) smpv(base, 0, j0, S0);
        if (has1) smpv(base, 1, j0 + 1, S1);
        asm volatile("s_barrier" ::: "memory");   // all waves done with buf
        if (kt + 2 < mx128) {
            stage(boff);                           // trip kt+2 -> same buf
            asm volatile("s_waitcnt vmcnt(4)" ::: "memory");  // kt+1 ready
        } else {
            asm volatile("s_waitcnt vmcnt(0)" ::: "memory");
        }
        asm volatile("s_barrier" ::: "memory");
        boff ^= 32768;
    }

    // epilogue: lane = query q0w+l31; O reg r -> d = dt*32+(r&3)+8*(r>>2)+4*hi
    const float lrow = l_ + __shfl_xor(l_, 32);
    const float inv = 1.f / lrow;
    const size_t grow = rbase + q0w + l31;
    #pragma unroll
    for (int dt = 0; dt < 2; ++dt)
        #pragma unroll
        for (int g2 = 0; g2 < 4; ++g2) {
            bf16x4v o4;
            #pragma unroll
            for (int j = 0; j < 4; ++j) o4[j] = (bf16_t)(O[dt][4 * g2 + j] * inv);
            const int d0 = dt * 32 + 8 * g2 + 4 * hi;
            *reinterpret_cast<bf16x4v*>(&ybf[grow * CC + hcol + d0]) = o4;
        }
}

// ---------------------------------------------------------------------------
extern "C" void kernel_launch(void* const* d_in, const int* in_sizes, int n_in,
                              void* d_out, int out_size, void* d_ws, size_t ws_size,
                              hipStream_t stream)
{
    (void)in_sizes; (void)n_in; (void)out_size; (void)ws_size;
    const float* x  = (const float*)d_in[0];
    const float* Wu = (const float*)d_in[1];
    const float* bu = (const float*)d_in[2];
    const float* Wv = (const float*)d_in[3];
    const float* bv = (const float*)d_in[4];
    const float* W1 = (const float*)d_in[5];
    const float* b1 = (const float*)d_in[6];
    const float* W2 = (const float*)d_in[7];
    const float* b2 = (const float*)d_in[8];
    const float* Wp = (const float*)d_in[9];
    const float* bp = (const float*)d_in[10];
    float* out = (float*)d_out;

    const size_t NE = (size_t)ROWS * CC;
    bf16_t* xbf = (bf16_t*)d_ws;                    // 16 MB
    bf16_t* ubf = xbf + NE;                         // 16 MB
    bf16_t* vp  = ubf + NE;                         // 16 MB
    bf16_t* vbT = vp  + NE;                         // 16 MB
    bf16_t* WuT = vbT + NE;                         // 2 MB  -- contiguous with
    bf16_t* WvT = WuT + (size_t)CC * CC;            // 2 MB  -- WuT: [2048][1024]
    bf16_t* WpT = WvT + (size_t)CC * CC;            // 2 MB
    bf16_t* W1T = WpT + (size_t)CC * CC;            // 8 KB
    bf16_t* W2T = W1T + (size_t)HS * HS;            // 8 KB
    bf16_t* ybf = vp;                               // alias: vp dead after gate

    prep_kernel<<<4865, 256, 0, stream>>>(
        x, xbf, Wu, Wv, Wp, WuT, WvT, WpT, W1, W2, W1T, W2T);

    mfma_gemm_uv8_kernel<<<256, 512, 0, stream>>>(
        xbf, WuT, bu, bv, ubf, vp);
    gate_mfma_kernel<<<dim3(ROWS / 64, HH), 256, 0, stream>>>(
        vp, W1T, W2T, b1, b2, vbT);
    attn_mfma18_kernel<<<512, 512, 0, stream>>>(ubf, xbf, vbT, ybf);
    mfma_gemm_out8_kernel<<<256, 512, 0, stream>>>(ybf, WpT, bp, out);
}

// Round 24
// 146.871 us; speedup vs baseline: 1.0274x; 1.0274x over previous
//
#include <hip/hip_runtime.h>
#include <hip/hip_bf16.h>
#include <math.h>

// Problem constants (B=4, T=2048, C=1024, H=16, HS=64)
#define BB 4
#define TT 2048
#define CC 1024
#define HH 16
#define HS 64
#define ROWS (BB*TT)          // 8192

typedef __bf16 bf16_t;
typedef __bf16 bf16x8 __attribute__((ext_vector_type(8)));
typedef __bf16 bf16x4v __attribute__((ext_vector_type(4)));
typedef __bf16 bf16x2 __attribute__((ext_vector_type(2)));
typedef float  f32x4  __attribute__((ext_vector_type(4)));
typedef float  f32x16 __attribute__((ext_vector_type(16)));
typedef unsigned u32x4 __attribute__((ext_vector_type(4)));

// async global->LDS, 16B per lane; LDS dest is wave-uniform base + lane*16
#define GLDS16(g, l) __builtin_amdgcn_global_load_lds( \
    (const __attribute__((address_space(1))) void*)(g), \
    (__attribute__((address_space(3))) void*)(l), 16, 0, 0)

#define KSCALE 0.04508422002778011f   /* (1/32) * log2(e), folded into u */
#define LOG2E  1.4426950408889634f

// raw HW exp2: single v_exp_f32 (args here are bounded; no denorm fixup needed)
#define EXP2R(x) __builtin_amdgcn_exp2f(x)

// ---------------------------------------------------------------------------
// Fused prep kernel: blocks 0..4095 = fp32->bf16 convert of x;
// 4096..4863 = 3x weight transpose+convert; 4864 = W1/W2 transpose.
// ---------------------------------------------------------------------------
__global__ __launch_bounds__(256) void prep_kernel(
    const float* __restrict__ x, bf16_t* __restrict__ xbf,
    const float* __restrict__ Wu, const float* __restrict__ Wv,
    const float* __restrict__ Wp,
    bf16_t* __restrict__ WuT, bf16_t* __restrict__ WvT, bf16_t* __restrict__ WpT,
    const float* __restrict__ W1, const float* __restrict__ W2,
    bf16_t* __restrict__ W1T, bf16_t* __restrict__ W2T)
{
    const int bid = blockIdx.x;
    const int tid = threadIdx.x;
    if (bid < 4096) {
        const size_t i = ((size_t)bid * 256 + tid) * 8;
        const float4 a = *reinterpret_cast<const float4*>(&x[i]);
        const float4 b = *reinterpret_cast<const float4*>(&x[i + 4]);
        bf16x8 o;
        o[0] = (bf16_t)a.x; o[1] = (bf16_t)a.y; o[2] = (bf16_t)a.z; o[3] = (bf16_t)a.w;
        o[4] = (bf16_t)b.x; o[5] = (bf16_t)b.y; o[6] = (bf16_t)b.z; o[7] = (bf16_t)b.w;
        *reinterpret_cast<bf16x8*>(&xbf[i]) = o;
    } else if (bid < 4864) {
        __shared__ float t[64][65];
        const int local = bid - 4096;
        const int m = local >> 8;
        const float* W = (m == 0) ? Wu : (m == 1) ? Wv : Wp;
        bf16_t* Wt = (m == 0) ? WuT : (m == 1) ? WvT : WpT;
        const int r0 = ((local >> 4) & 15) * 64, c0 = (local & 15) * 64;
        #pragma unroll
        for (int l = 0; l < 16; ++l) {
            int idx = tid + l * 256;
            int rr = idx >> 6, cc = idx & 63;
            t[rr][cc] = W[(size_t)(r0 + rr) * CC + c0 + cc];
        }
        __syncthreads();
        #pragma unroll
        for (int l = 0; l < 16; ++l) {
            int idx = tid + l * 256;
            int rr = idx >> 6, cc = idx & 63;
            Wt[(size_t)(c0 + rr) * CC + r0 + cc] = (bf16_t)t[cc][rr];
        }
    } else {
        __shared__ float t1[64][65], t2[64][65];
        #pragma unroll
        for (int l = 0; l < 16; ++l) {
            int idx = tid + l * 256;
            int rr = idx >> 6, cc = idx & 63;
            t1[rr][cc] = W1[idx]; t2[rr][cc] = W2[idx];
        }
        __syncthreads();
        #pragma unroll
        for (int l = 0; l < 16; ++l) {
            int idx = tid + l * 256;
            int rr = idx >> 6, cc = idx & 63;
            W1T[idx] = (bf16_t)t1[cc][rr];
            W2T[idx] = (bf16_t)t2[cc][rr];
        }
    }
}

// ---------------------------------------------------------------------------
// 256x256 8-phase uv GEMM (T3+T4+T5 + T1 XCD swizzle):
//   [u|v] = A @ [WuT||WvT]^T + [bu|bv].
// ---------------------------------------------------------------------------
__global__ __launch_bounds__(512, 2) void mfma_gemm_uv8_kernel(
    const bf16_t* __restrict__ A, const bf16_t* __restrict__ Bt,
    const float* __restrict__ bu, const float* __restrict__ bv,
    bf16_t* __restrict__ uout, bf16_t* __restrict__ vout)
{
    __shared__ __align__(16) char smem[131072];   // [buf][A 32K | B 32K]
    const int tid = threadIdx.x;
    const int wave = tid >> 6, lane = tid & 63;
    const int bid = (int)blockIdx.x;              // 0..255
    const int xcd = bid & 7, lid = bid >> 3;      // 32 blocks per XCD
    const int xq = (xcd & 1) * 4 + (lid & 3);     // col-block 0..7
    const int yq = (xcd >> 1) * 8 + (lid >> 2);   // row-block 0..31
    const int row0 = yq * 256, col0 = xq * 256;
    const int wm = wave >> 2, wn = wave & 3;      // 2 x 4 wave grid
    const int lr = lane & 15, ko = lane >> 4;
    const int koff = ((lane & 7) ^ (lane >> 3)) << 3;   // staging inverse swz
    const int rsub = lane >> 3;

    int rdc[2];
    #pragma unroll
    for (int ks = 0; ks < 2; ++ks)
        rdc[ks] = ((((ks << 2) + ko) ^ (lr & 7)) << 4);
    const int arow = (wm << 7) + lr;
    const int brow = (wn << 6) + lr;

    f32x4 acc[8][4];
    #pragma unroll
    for (int i = 0; i < 8; ++i)
        #pragma unroll
        for (int j = 0; j < 4; ++j) acc[i][j] = (f32x4){0.f, 0.f, 0.f, 0.f};

    auto stageA = [&](int t, int bufbase) {       // 4 A loads per wave
        const int k0 = t << 6;
        const bf16_t* ag = A + (size_t)(row0 + wave * 8 + rsub) * CC + k0 + koff;
        char* da = smem + bufbase + wave * 1024;
        #pragma unroll
        for (int a = 0; a < 4; ++a) {
            GLDS16(ag, da);
            ag += 64 * CC; da += 8192;
        }
    };
    auto stageB = [&](int t, int bufbase) {       // 4 B loads per wave
        const int k0 = t << 6;
        const bf16_t* bg = Bt + (size_t)(col0 + wave * 8 + rsub) * CC + k0 + koff;
        char* db = smem + bufbase + 32768 + wave * 1024;
        #pragma unroll
        for (int a = 0; a < 4; ++a) {
            GLDS16(bg, db);
            bg += 64 * CC; db += 8192;
        }
    };

    bf16x8 bfr[4][2];
    auto phase = [&](int bufbase, int mi0, bool withB) {
        const char* sA = smem + bufbase;
        const char* sB = smem + bufbase + 32768;
        if (withB) {
            #pragma unroll
            for (int ni = 0; ni < 4; ++ni)
                #pragma unroll
                for (int ks = 0; ks < 2; ++ks)
                    bfr[ni][ks] = *reinterpret_cast<const bf16x8*>(
                        sB + (brow + ni * 16) * 128 + rdc[ks]);
        }
        bf16x8 af[2][2];
        #pragma unroll
        for (int m2 = 0; m2 < 2; ++m2)
            #pragma unroll
            for (int ks = 0; ks < 2; ++ks)
                af[m2][ks] = *reinterpret_cast<const bf16x8*>(
                    sA + (arow + (mi0 + m2) * 16) * 128 + rdc[ks]);
        __builtin_amdgcn_s_setprio(1);
        #pragma unroll
        for (int m2 = 0; m2 < 2; ++m2)
            #pragma unroll
            for (int ni = 0; ni < 4; ++ni)
                #pragma unroll
                for (int ks = 0; ks < 2; ++ks)
                    acc[mi0 + m2][ni] = __builtin_amdgcn_mfma_f32_16x16x32_bf16(
                        af[m2][ks], bfr[ni][ks], acc[mi0 + m2][ni], 0, 0, 0);
        __builtin_amdgcn_s_setprio(0);
        asm volatile("s_barrier" ::: "memory");
    };

    stageA(0, 0);     stageB(0, 0);
    stageA(1, 65536); stageB(1, 65536);
    asm volatile("s_waitcnt vmcnt(8)" ::: "memory");
    asm volatile("s_barrier" ::: "memory");

    for (int i = 0; i < 8; ++i) {
        const int t0 = 2 * i;
        phase(0, 0, true);
        if (t0 + 2 < 16) stageB(t0 + 2, 0);          // B region dead after ph1
        phase(0, 2, false); phase(0, 4, false); phase(0, 6, false);
        if (t0 + 2 < 16) {
            stageA(t0 + 2, 0);
            asm volatile("s_waitcnt vmcnt(8)" ::: "memory");   // t0+1 ready
        } else {
            asm volatile("s_waitcnt vmcnt(0)" ::: "memory");
        }
        asm volatile("s_barrier" ::: "memory");
        phase(65536, 0, true);
        if (t0 + 3 < 16) stageB(t0 + 3, 65536);
        phase(65536, 2, false); phase(65536, 4, false); phase(65536, 6, false);
        if (t0 + 3 < 16) {
            stageA(t0 + 3, 65536);
            asm volatile("s_waitcnt vmcnt(8)" ::: "memory");   // t0+2 ready
            asm volatile("s_barrier" ::: "memory");
        }
    }

    const bool isU = (col0 < 1024);
    const float* const bias = isU ? bu : bv;
    const float scl = isU ? KSCALE : 1.0f;
    bf16_t* const outp = isU ? uout : vout;
    const int cbase = col0 & 1023;

    float bv4[4];
    #pragma unroll
    for (int ni = 0; ni < 4; ++ni)
        bv4[ni] = bias[cbase + wn * 64 + ni * 16 + lr];
    #pragma unroll
    for (int mi = 0; mi < 8; ++mi)
        #pragma unroll
        for (int j = 0; j < 4; ++j) {
            const int grow = row0 + wm * 128 + mi * 16 + ko * 4 + j;
            #pragma unroll
            for (int ni = 0; ni < 4; ++ni) {
                const int gcol = cbase + wn * 64 + ni * 16 + lr;
                outp[(size_t)grow * CC + gcol] =
                    (bf16_t)((acc[mi][ni][j] + bv4[ni]) * scl);
            }
        }
}

// ---------------------------------------------------------------------------
// 256x128 8-phase out GEMM (+ T1 XCD swizzle): out = ybf @ WpT + bp (fp32)
// ---------------------------------------------------------------------------
__global__ __launch_bounds__(512, 1) void mfma_gemm_out8_kernel(
    const bf16_t* __restrict__ A, const bf16_t* __restrict__ Bt,
    const float* __restrict__ bias, float* __restrict__ Cout)
{
    __shared__ __align__(16) char smem[98304];    // buf b at b*49152: A 32K, B 16K
    const int tid = threadIdx.x;
    const int wave = tid >> 6, lane = tid & 63;
    const int bid = (int)blockIdx.x;              // 0..255
    const int xcd = bid & 7, lid = bid >> 3;
    const int xq = (xcd & 1) * 4 + (lid & 3);     // col-block 0..7
    const int yq = (xcd >> 1) * 8 + (lid >> 2);   // row-block 0..31
    const int row0 = yq * 256, col0 = xq * 128;
    const int wm = wave >> 2, wn = wave & 3;
    const int lr = lane & 15, ko = lane >> 4;
    const int koff = ((lane & 7) ^ (lane >> 3)) << 3;
    const int rsub = lane >> 3;

    int rdc[2];
    #pragma unroll
    for (int ks = 0; ks < 2; ++ks)
        rdc[ks] = ((((ks << 2) + ko) ^ (lr & 7)) << 4);
    const int arow = (wm << 7) + lr;
    const int brow = (wn << 5) + lr;

    f32x4 acc[8][2];
    #pragma unroll
    for (int i = 0; i < 8; ++i)
        #pragma unroll
        for (int j = 0; j < 2; ++j) acc[i][j] = (f32x4){0.f, 0.f, 0.f, 0.f};

    auto stage = [&](int t, int bufbase) {
        const int k0 = t << 6;
        const bf16_t* ag = A + (size_t)(row0 + wave * 8 + rsub) * CC + k0 + koff;
        char* da = smem + bufbase + wave * 1024;
        #pragma unroll
        for (int a = 0; a < 4; ++a) {
            GLDS16(ag, da);
            ag += 64 * CC; da += 8192;
        }
        const bf16_t* bg = Bt + (size_t)(col0 + wave * 8 + rsub) * CC + k0 + koff;
        char* db = smem + bufbase + 32768 + wave * 1024;
        GLDS16(bg, db);
        GLDS16(bg + (size_t)64 * CC, db + 8192);
    };

    bf16x8 bfr[2][2];
    auto phase = [&](int bufbase, int mi0, bool withB) {
        const char* sA = smem + bufbase;
        const char* sB = smem + bufbase + 32768;
        if (withB) {
            #pragma unroll
            for (int ni = 0; ni < 2; ++ni)
                #pragma unroll
                for (int ks = 0; ks < 2; ++ks)
                    bfr[ni][ks] = *reinterpret_cast<const bf16x8*>(
                        sB + (brow + ni * 16) * 128 + rdc[ks]);
        }
        bf16x8 af[2][2];
        #pragma unroll
        for (int m2 = 0; m2 < 2; ++m2)
            #pragma unroll
            for (int ks = 0; ks < 2; ++ks)
                af[m2][ks] = *reinterpret_cast<const bf16x8*>(
                    sA + (arow + (mi0 + m2) * 16) * 128 + rdc[ks]);
        __builtin_amdgcn_s_setprio(1);
        #pragma unroll
        for (int m2 = 0; m2 < 2; ++m2)
            #pragma unroll
            for (int ni = 0; ni < 2; ++ni)
                #pragma unroll
                for (int ks = 0; ks < 2; ++ks)
                    acc[mi0 + m2][ni] = __builtin_amdgcn_mfma_f32_16x16x32_bf16(
                        af[m2][ks], bfr[ni][ks], acc[mi0 + m2][ni], 0, 0, 0);
        __builtin_amdgcn_s_setprio(0);
        asm volatile("s_barrier" ::: "memory");
    };

    stage(0, 0);
    stage(1, 49152);
    asm volatile("s_waitcnt vmcnt(6)" ::: "memory");
    asm volatile("s_barrier" ::: "memory");

    for (int i = 0; i < 8; ++i) {
        const int t0 = 2 * i;
        phase(0, 0, true); phase(0, 2, false); phase(0, 4, false); phase(0, 6, false);
        if (t0 + 2 < 16) {
            stage(t0 + 2, 0);
            asm volatile("s_waitcnt vmcnt(6)" ::: "memory");
        } else {
            asm volatile("s_waitcnt vmcnt(0)" ::: "memory");
        }
        asm volatile("s_barrier" ::: "memory");
        phase(49152, 0, true); phase(49152, 2, false);
        phase(49152, 4, false); phase(49152, 6, false);
        if (t0 + 3 < 16) {
            stage(t0 + 3, 49152);
            asm volatile("s_waitcnt vmcnt(6)" ::: "memory");
            asm volatile("s_barrier" ::: "memory");
        }
    }

    float bv2[2];
    #pragma unroll
    for (int ni = 0; ni < 2; ++ni)
        bv2[ni] = bias[col0 + wn * 32 + ni * 16 + lr];
    #pragma unroll
    for (int mi = 0; mi < 8; ++mi)
        #pragma unroll
        for (int j = 0; j < 4; ++j) {
            const int grow = row0 + wm * 128 + mi * 16 + ko * 4 + j;
            #pragma unroll
            for (int ni = 0; ni < 2; ++ni) {
                const int gcol = col0 + wn * 32 + ni * 16 + lr;
                Cout[(size_t)grow * CC + gcol] = acc[mi][ni][j] + bv2[ni];
            }
        }
}

// ---------------------------------------------------------------------------
// MFMA gated transform, transposed output -> vbT [B*H][64][TT] (kappa cols).
// ---------------------------------------------------------------------------
__global__ __launch_bounds__(256) void gate_mfma_kernel(
    const bf16_t* __restrict__ vp,
    const bf16_t* __restrict__ W1T, const bf16_t* __restrict__ W2T,
    const float* __restrict__ b1, const float* __restrict__ b2,
    bf16_t* __restrict__ vbT)
{
    __shared__ __align__(16) bf16_t Vs[64][64];
    const int tid = threadIdx.x, wave = tid >> 6, lane = tid & 63;
    const int t0 = blockIdx.x * 64;
    const int h = blockIdx.y;
    const int lr = lane & 15, ko = lane >> 4;
    const int koff = ((lane & 7) ^ (lane >> 3)) << 3;
    const int rsub = lane >> 3;

    #pragma unroll
    for (int i = 0; i < 2; ++i) {
        const int rb = (wave * 2 + i) * 8;
        GLDS16(vp + (size_t)(t0 + rb + rsub) * CC + h * 64 + koff,
               (char*)&Vs[rb][0]);
    }
    asm volatile("s_waitcnt vmcnt(0)" ::: "memory");
    __syncthreads();

    bf16x8 w1f[4][2], w2f[4][2];
    #pragma unroll
    for (int ni = 0; ni < 4; ++ni)
        #pragma unroll
        for (int kc = 0; kc < 2; ++kc) {
            w1f[ni][kc] = *reinterpret_cast<const bf16x8*>(
                &W1T[(ni * 16 + lr) * 64 + kc * 32 + ko * 8]);
            w2f[ni][kc] = *reinterpret_cast<const bf16x8*>(
                &W2T[(ni * 16 + lr) * 64 + kc * 32 + ko * 8]);
        }
    const int trow = wave * 16 + lr;
    bf16x8 vf[2];
    #pragma unroll
    for (int kc = 0; kc < 2; ++kc)
        vf[kc] = *reinterpret_cast<const bf16x8*>(
            (char*)Vs + trow * 128 + ((((kc << 2) + ko) ^ (trow & 7)) << 4));

    f32x4 Aacc[4], Gacc[4];
    #pragma unroll
    for (int ni = 0; ni < 4; ++ni) {
        Aacc[ni] = (f32x4){0.f, 0.f, 0.f, 0.f};
        Gacc[ni] = (f32x4){0.f, 0.f, 0.f, 0.f};
    }
    #pragma unroll
    for (int ni = 0; ni < 4; ++ni)
        #pragma unroll
        for (int kc = 0; kc < 2; ++kc) {
            Aacc[ni] = __builtin_amdgcn_mfma_f32_16x16x32_bf16(
                w1f[ni][kc], vf[kc], Aacc[ni], 0, 0, 0);
            Gacc[ni] = __builtin_amdgcn_mfma_f32_16x16x32_bf16(
                w2f[ni][kc], vf[kc], Gacc[ni], 0, 0, 0);
        }

    const int bidx = t0 >> 11;
    const int q2 = (lr >> 2) & 3;
    const int lrk = lr + (q2 == 1 ? 4 : (q2 == 2 ? -4 : 0));
    const int tb = (t0 & 2047) + wave * 16 + lrk;
    const size_t obase = (size_t)(bidx * HH + h) * HS * TT;
    #pragma unroll
    for (int ni = 0; ni < 4; ++ni)
        #pragma unroll
        for (int j = 0; j < 4; ++j) {
            const int d = ni * 16 + ko * 4 + j;
            const float vterm = (float)*(const bf16_t*)(
                (const char*)Vs + trow * 128 +
                ((((d >> 3) ^ (trow & 7)) << 4) + (d & 7) * 2));
            const float a = Aacc[ni][j] + b1[d];
            const float g = Gacc[ni][j] + b2[d];
            const float val = (vterm + a) * (1.f / (1.f + EXP2R(-g * LOG2E)));
            vbT[obase + (size_t)d * TT + tb] = (bf16_t)val;
        }
}

// ---------------------------------------------------------------------------
// MFMA flash attention v17: 8 waves (512 thr) x 32 q = 256-row q-blocks,
// KVBLK=128 staging shared by 8 waves, 2 blocks/CU -> 4 waves/SIMD.
// Static balanced mapping; counted vmcnt(4); raw barriers; no-max softmax
// (EXP2R); lane-local P; kappa-staged V^T; 32x32 swapped MFMA; setprio.
// ---------------------------------------------------------------------------
__global__ __launch_bounds__(512) void attn_mfma17_kernel(
    const bf16_t* __restrict__ ubf, const bf16_t* __restrict__ xbf,
    const bf16_t* __restrict__ vbT, bf16_t* __restrict__ ybf)
{
    __shared__ __align__(16) char KV[2 * 32768];   // buf b at b*32768: K 16K, V 16K

    const int tid = threadIdx.x, wave = tid >> 6, lane = tid & 63;
    const int l31 = lane & 31, hi = lane >> 5;
    const int koff = ((lane & 7) ^ (lane >> 3)) << 3;   // K staging inverse swz
    const int rsub = lane >> 3;

    // static balanced work mapping (18 trips/CU, heavy first)
    const int w = (int)blockIdx.x;          // 0..511
    const int s = w >> 8;                   // start order 0/1
    const int m = (w >> 6) & 3;
    const int qg = s ? m : 7 - m;           // pairs {m, 7-m}
    const int h = w & 15, b = (w >> 4) & 3;

    int lak[4], lav[4];
    #pragma unroll
    for (int cc = 0; cc < 4; ++cc) {
        const int xr = ((2 * cc + hi) ^ (l31 & 7)) << 4;
        lak[cc] = l31 * 128 + xr;
        lav[cc] = l31 * 256 + xr;
    }
    const int voffA = (((lane & 15) ^ (lane >> 4)) << 3);
    const int voffB = (((lane & 15) ^ ((lane >> 4) + 4)) << 3);

    f32x16 zero16;
    #pragma unroll
    for (int r = 0; r < 16; ++r) zero16[r] = 0.f;

    const int q0w = qg * 256 + wave * 32;
    const size_t rbase = (size_t)b * TT;
    const int hcol = h * 64;
    const size_t hVT = (size_t)(b * HH + h) * HS * TT;

    bf16x8 qf[4];
    #pragma unroll
    for (int dk = 0; dk < 4; ++dk)
        qf[dk] = *reinterpret_cast<const bf16x8*>(
            &ubf[(rbase + q0w + l31) * CC + hcol + dk * 16 + hi * 8]);

    f32x16 O[2];
    #pragma unroll
    for (int dt = 0; dt < 2; ++dt)
        #pragma unroll
        for (int r = 0; r < 16; ++r) O[dt][r] = 0.f;
    float l_ = 0.f;

    const int myn64 = (q0w + 95) >> 6;      // 64-key tiles needed
    const int mx128 = 2 * qg + 2;           // 128-key trips (>= 2)

    const bf16_t* xsK = xbf + (rbase + wave * 16 + rsub) * CC + hcol + koff;
    const bf16_t* vsA = vbT + hVT + (size_t)(wave * 8 + (lane >> 4)) * TT + voffA;
    const bf16_t* vsB = vbT + hVT + (size_t)(wave * 8 + (lane >> 4)) * TT + voffB;

    auto stage = [&](int bufbase) {         // 4 GLDS16 calls per wave
        char* dK = KV + bufbase + wave * 2048;          // K rows wave*16..+16
        GLDS16(xsK,          dK);
        GLDS16(xsK + 8 * CC, dK + 1024);
        char* dV = KV + bufbase + 16384 + wave * 2048;  // V rows wave*8..+8
        GLDS16(vsA,          dV);
        GLDS16(vsB + 4 * TT, dV + 1024);
        xsK += 128 * CC; vsA += 128; vsB += 128;
    };

    auto compute_sub = [&](int bufbase, int ss, int j) {  // 64-key sub-tile
        const char* const base = KV + bufbase;
        f32x16 S[2];
        __builtin_amdgcn_s_setprio(1);
        #pragma unroll
        for (int kb = 0; kb < 2; ++kb) {
            f32x16 sv = __builtin_amdgcn_mfma_f32_32x32x16_bf16(
                *reinterpret_cast<const bf16x8*>(
                    base + ss * 8192 + kb * 4096 + lak[0]),
                qf[0], zero16, 0, 0, 0);
            #pragma unroll
            for (int dk = 1; dk < 4; ++dk)
                sv = __builtin_amdgcn_mfma_f32_32x32x16_bf16(
                    *reinterpret_cast<const bf16x8*>(
                        base + ss * 8192 + kb * 4096 + lak[dk]),
                    qf[dk], sv, 0, 0, 0);
            S[kb] = sv;
        }
        __builtin_amdgcn_s_setprio(0);

        if (j == myn64 - 1) {               // causal mask, diagonal tile only
            const int k0 = j * 64;
            const int q = q0w + l31;
            #pragma unroll
            for (int kb = 0; kb < 2; ++kb)
                #pragma unroll
                for (int r = 0; r < 16; ++r) {
                    const int key = k0 + kb * 32 + (r & 3) + 8 * (r >> 2) + 4 * hi;
                    if (key > q) S[kb][r] = -1e30f;
                }
        }

        unsigned pw[2][4][2];
        float ps0 = 0.f, ps1 = 0.f;
        #pragma unroll
        for (int kb = 0; kb < 2; ++kb)
            #pragma unroll
            for (int gq = 0; gq < 4; ++gq)
                #pragma unroll
                for (int jj = 0; jj < 2; ++jj) {
                    const float p0 = EXP2R(S[kb][4 * gq + 2 * jj + 0]);
                    const float p1 = EXP2R(S[kb][4 * gq + 2 * jj + 1]);
                    ps0 += p0; ps1 += p1;
                    bf16x2 t; t[0] = (bf16_t)p0; t[1] = (bf16_t)p1;
                    pw[kb][gq][jj] = __builtin_bit_cast(unsigned, t);
                }
        l_ += ps0 + ps1;

        bf16x8 pfr[2][2];
        #pragma unroll
        for (int kb = 0; kb < 2; ++kb)
            #pragma unroll
            for (int ks = 0; ks < 2; ++ks) {
                u32x4 fw = {pw[kb][2 * ks][0], pw[kb][2 * ks][1],
                            pw[kb][2 * ks + 1][0], pw[kb][2 * ks + 1][1]};
                pfr[kb][ks] = __builtin_bit_cast(bf16x8, fw);
            }

        __builtin_amdgcn_s_setprio(1);
        #pragma unroll
        for (int dt = 0; dt < 2; ++dt)
            #pragma unroll
            for (int kb = 0; kb < 2; ++kb)
                #pragma unroll
                for (int ks = 0; ks < 2; ++ks) {
                    const bf16x8 vt = *reinterpret_cast<const bf16x8*>(
                        base + 16384 + dt * 8192 + ss * 128 + lav[2 * kb + ks]);
                    O[dt] = __builtin_amdgcn_mfma_f32_32x32x16_bf16(
                        vt, pfr[kb][ks], O[dt], 0, 0, 0);
                }
        __builtin_amdgcn_s_setprio(0);
    };

    // prologue: stage trips 0 (buf0) and 1 (buf1; mx128 >= 2 always)
    stage(0);
    stage(32768);
    asm volatile("s_waitcnt vmcnt(4)" ::: "memory");   // qf + trip0 done
    asm volatile("s_barrier" ::: "memory");

    int boff = 0;
    for (int kt = 0; kt < mx128; ++kt) {
        const int j0 = 2 * kt;
        if (j0 < myn64)     compute_sub(boff, 0, j0);
        if (j0 + 1 < myn64) compute_sub(boff, 1, j0 + 1);
        asm volatile("s_barrier" ::: "memory");   // all waves done with buf
        if (kt + 2 < mx128) {
            stage(boff);                           // trip kt+2 -> same buf
            asm volatile("s_waitcnt vmcnt(4)" ::: "memory");  // kt+1 ready
        } else {
            asm volatile("s_waitcnt vmcnt(0)" ::: "memory");
        }
        asm volatile("s_barrier" ::: "memory");
        boff ^= 32768;
    }

    // epilogue: lane = query q0w+l31; O reg r -> d = dt*32+(r&3)+8*(r>>2)+4*hi
    const float lrow = l_ + __shfl_xor(l_, 32);
    const float inv = 1.f / lrow;
    const size_t grow = rbase + q0w + l31;
    #pragma unroll
    for (int dt = 0; dt < 2; ++dt)
        #pragma unroll
        for (int g2 = 0; g2 < 4; ++g2) {
            bf16x4v o4;
            #pragma unroll
            for (int j = 0; j < 4; ++j) o4[j] = (bf16_t)(O[dt][4 * g2 + j] * inv);
            const int d0 = dt * 32 + 8 * g2 + 4 * hi;
            *reinterpret_cast<bf16x4v*>(&ybf[grow * CC + hcol + d0]) = o4;
        }
}

// ---------------------------------------------------------------------------
extern "C" void kernel_launch(void* const* d_in, const int* in_sizes, int n_in,
                              void* d_out, int out_size, void* d_ws, size_t ws_size,
                              hipStream_t stream)
{
    (void)in_sizes; (void)n_in; (void)out_size; (void)ws_size;
    const float* x  = (const float*)d_in[0];
    const float* Wu = (const float*)d_in[1];
    const float* bu = (const float*)d_in[2];
    const float* Wv = (const float*)d_in[3];
    const float* bv = (const float*)d_in[4];
    const float* W1 = (const float*)d_in[5];
    const float* b1 = (const float*)d_in[6];
    const float* W2 = (const float*)d_in[7];
    const float* b2 = (const float*)d_in[8];
    const float* Wp = (const float*)d_in[9];
    const float* bp = (const float*)d_in[10];
    float* out = (float*)d_out;

    const size_t NE = (size_t)ROWS * CC;
    bf16_t* xbf = (bf16_t*)d_ws;                    // 16 MB
    bf16_t* ubf = xbf + NE;                         // 16 MB
    bf16_t* vp  = ubf + NE;                         // 16 MB
    bf16_t* vbT = vp  + NE;                         // 16 MB
    bf16_t* WuT = vbT + NE;                         // 2 MB  -- contiguous with
    bf16_t* WvT = WuT + (size_t)CC * CC;            // 2 MB  -- WuT: [2048][1024]
    bf16_t* WpT = WvT + (size_t)CC * CC;            // 2 MB
    bf16_t* W1T = WpT + (size_t)CC * CC;            // 8 KB
    bf16_t* W2T = W1T + (size_t)HS * HS;            // 8 KB
    bf16_t* ybf = vp;                               // alias: vp dead after gate

    prep_kernel<<<4865, 256, 0, stream>>>(
        x, xbf, Wu, Wv, Wp, WuT, WvT, WpT, W1, W2, W1T, W2T);

    mfma_gemm_uv8_kernel<<<256, 512, 0, stream>>>(
        xbf, WuT, bu, bv, ubf, vp);
    gate_mfma_kernel<<<dim3(ROWS / 64, HH), 256, 0, stream>>>(
        vp, W1T, W2T, b1, b2, vbT);
    attn_mfma17_kernel<<<512, 512, 0, stream>>>(ubf, xbf, vbT, ybf);
    mfma_gemm_out8_kernel<<<256, 512, 0, stream>>>(ybf, WpT, bp, out);
}

// Round 25
// 143.633 us; speedup vs baseline: 1.0506x; 1.0225x over previous
//
#include <hip/hip_runtime.h>
#include <hip/hip_bf16.h>
#include <math.h>

// Problem constants (B=4, T=2048, C=1024, H=16, HS=64)
#define BB 4
#define TT 2048
#define CC 1024
#define HH 16
#define HS 64
#define ROWS (BB*TT)          // 8192

typedef __bf16 bf16_t;
typedef __bf16 bf16x8 __attribute__((ext_vector_type(8)));
typedef __bf16 bf16x4v __attribute__((ext_vector_type(4)));
typedef __bf16 bf16x2 __attribute__((ext_vector_type(2)));
typedef float  f32x4  __attribute__((ext_vector_type(4)));
typedef float  f32x16 __attribute__((ext_vector_type(16)));
typedef unsigned u32x4 __attribute__((ext_vector_type(4)));

// async global->LDS, 16B per lane; LDS dest is wave-uniform base + lane*16
#define GLDS16(g, l) __builtin_amdgcn_global_load_lds( \
    (const __attribute__((address_space(1))) void*)(g), \
    (__attribute__((address_space(3))) void*)(l), 16, 0, 0)

#define KSCALE 0.04508422002778011f   /* (1/32) * log2(e), folded into u */
#define LOG2E  1.4426950408889634f

// raw HW exp2: single v_exp_f32 (args here are bounded; no denorm fixup needed)
#define EXP2R(x) __builtin_amdgcn_exp2f(x)

// ---------------------------------------------------------------------------
// Fused prep kernel: blocks 0..4095 = fp32->bf16 convert of x;
// 4096..4863 = 3x weight transpose+convert; 4864 = W1/W2 transpose.
// ---------------------------------------------------------------------------
__global__ __launch_bounds__(256) void prep_kernel(
    const float* __restrict__ x, bf16_t* __restrict__ xbf,
    const float* __restrict__ Wu, const float* __restrict__ Wv,
    const float* __restrict__ Wp,
    bf16_t* __restrict__ WuT, bf16_t* __restrict__ WvT, bf16_t* __restrict__ WpT,
    const float* __restrict__ W1, const float* __restrict__ W2,
    bf16_t* __restrict__ W1T, bf16_t* __restrict__ W2T)
{
    const int bid = blockIdx.x;
    const int tid = threadIdx.x;
    if (bid < 4096) {
        const size_t i = ((size_t)bid * 256 + tid) * 8;
        const float4 a = *reinterpret_cast<const float4*>(&x[i]);
        const float4 b = *reinterpret_cast<const float4*>(&x[i + 4]);
        bf16x8 o;
        o[0] = (bf16_t)a.x; o[1] = (bf16_t)a.y; o[2] = (bf16_t)a.z; o[3] = (bf16_t)a.w;
        o[4] = (bf16_t)b.x; o[5] = (bf16_t)b.y; o[6] = (bf16_t)b.z; o[7] = (bf16_t)b.w;
        *reinterpret_cast<bf16x8*>(&xbf[i]) = o;
    } else if (bid < 4864) {
        __shared__ float t[64][65];
        const int local = bid - 4096;
        const int m = local >> 8;
        const float* W = (m == 0) ? Wu : (m == 1) ? Wv : Wp;
        bf16_t* Wt = (m == 0) ? WuT : (m == 1) ? WvT : WpT;
        const int r0 = ((local >> 4) & 15) * 64, c0 = (local & 15) * 64;
        #pragma unroll
        for (int l = 0; l < 16; ++l) {
            int idx = tid + l * 256;
            int rr = idx >> 6, cc = idx & 63;
            t[rr][cc] = W[(size_t)(r0 + rr) * CC + c0 + cc];
        }
        __syncthreads();
        #pragma unroll
        for (int l = 0; l < 16; ++l) {
            int idx = tid + l * 256;
            int rr = idx >> 6, cc = idx & 63;
            Wt[(size_t)(c0 + rr) * CC + r0 + cc] = (bf16_t)t[cc][rr];
        }
    } else {
        __shared__ float t1[64][65], t2[64][65];
        #pragma unroll
        for (int l = 0; l < 16; ++l) {
            int idx = tid + l * 256;
            int rr = idx >> 6, cc = idx & 63;
            t1[rr][cc] = W1[idx]; t2[rr][cc] = W2[idx];
        }
        __syncthreads();
        #pragma unroll
        for (int l = 0; l < 16; ++l) {
            int idx = tid + l * 256;
            int rr = idx >> 6, cc = idx & 63;
            W1T[idx] = (bf16_t)t1[cc][rr];
            W2T[idx] = (bf16_t)t2[cc][rr];
        }
    }
}

// ---------------------------------------------------------------------------
// 256x256 8-phase uv GEMM (T3+T4+T5 + T1 XCD swizzle):
//   [u|v] = A @ [WuT||WvT]^T + [bu|bv].
// ---------------------------------------------------------------------------
__global__ __launch_bounds__(512, 2) void mfma_gemm_uv8_kernel(
    const bf16_t* __restrict__ A, const bf16_t* __restrict__ Bt,
    const float* __restrict__ bu, const float* __restrict__ bv,
    bf16_t* __restrict__ uout, bf16_t* __restrict__ vout)
{
    __shared__ __align__(16) char smem[131072];   // [buf][A 32K | B 32K]
    const int tid = threadIdx.x;
    const int wave = tid >> 6, lane = tid & 63;
    const int bid = (int)blockIdx.x;              // 0..255
    const int xcd = bid & 7, lid = bid >> 3;      // 32 blocks per XCD
    const int xq = (xcd & 1) * 4 + (lid & 3);     // col-block 0..7
    const int yq = (xcd >> 1) * 8 + (lid >> 2);   // row-block 0..31
    const int row0 = yq * 256, col0 = xq * 256;
    const int wm = wave >> 2, wn = wave & 3;      // 2 x 4 wave grid
    const int lr = lane & 15, ko = lane >> 4;
    const int koff = ((lane & 7) ^ (lane >> 3)) << 3;   // staging inverse swz
    const int rsub = lane >> 3;

    int rdc[2];
    #pragma unroll
    for (int ks = 0; ks < 2; ++ks)
        rdc[ks] = ((((ks << 2) + ko) ^ (lr & 7)) << 4);
    const int arow = (wm << 7) + lr;
    const int brow = (wn << 6) + lr;

    f32x4 acc[8][4];
    #pragma unroll
    for (int i = 0; i < 8; ++i)
        #pragma unroll
        for (int j = 0; j < 4; ++j) acc[i][j] = (f32x4){0.f, 0.f, 0.f, 0.f};

    auto stageA = [&](int t, int bufbase) {       // 4 A loads per wave
        const int k0 = t << 6;
        const bf16_t* ag = A + (size_t)(row0 + wave * 8 + rsub) * CC + k0 + koff;
        char* da = smem + bufbase + wave * 1024;
        #pragma unroll
        for (int a = 0; a < 4; ++a) {
            GLDS16(ag, da);
            ag += 64 * CC; da += 8192;
        }
    };
    auto stageB = [&](int t, int bufbase) {       // 4 B loads per wave
        const int k0 = t << 6;
        const bf16_t* bg = Bt + (size_t)(col0 + wave * 8 + rsub) * CC + k0 + koff;
        char* db = smem + bufbase + 32768 + wave * 1024;
        #pragma unroll
        for (int a = 0; a < 4; ++a) {
            GLDS16(bg, db);
            bg += 64 * CC; db += 8192;
        }
    };

    bf16x8 bfr[4][2];
    auto phase = [&](int bufbase, int mi0, bool withB) {
        const char* sA = smem + bufbase;
        const char* sB = smem + bufbase + 32768;
        if (withB) {
            #pragma unroll
            for (int ni = 0; ni < 4; ++ni)
                #pragma unroll
                for (int ks = 0; ks < 2; ++ks)
                    bfr[ni][ks] = *reinterpret_cast<const bf16x8*>(
                        sB + (brow + ni * 16) * 128 + rdc[ks]);
        }
        bf16x8 af[2][2];
        #pragma unroll
        for (int m2 = 0; m2 < 2; ++m2)
            #pragma unroll
            for (int ks = 0; ks < 2; ++ks)
                af[m2][ks] = *reinterpret_cast<const bf16x8*>(
                    sA + (arow + (mi0 + m2) * 16) * 128 + rdc[ks]);
        __builtin_amdgcn_s_setprio(1);
        #pragma unroll
        for (int m2 = 0; m2 < 2; ++m2)
            #pragma unroll
            for (int ni = 0; ni < 4; ++ni)
                #pragma unroll
                for (int ks = 0; ks < 2; ++ks)
                    acc[mi0 + m2][ni] = __builtin_amdgcn_mfma_f32_16x16x32_bf16(
                        af[m2][ks], bfr[ni][ks], acc[mi0 + m2][ni], 0, 0, 0);
        __builtin_amdgcn_s_setprio(0);
        asm volatile("s_barrier" ::: "memory");
    };

    stageA(0, 0);     stageB(0, 0);
    stageA(1, 65536); stageB(1, 65536);
    asm volatile("s_waitcnt vmcnt(8)" ::: "memory");
    asm volatile("s_barrier" ::: "memory");

    for (int i = 0; i < 8; ++i) {
        const int t0 = 2 * i;
        phase(0, 0, true);
        if (t0 + 2 < 16) stageB(t0 + 2, 0);          // B region dead after ph1
        phase(0, 2, false); phase(0, 4, false); phase(0, 6, false);
        if (t0 + 2 < 16) {
            stageA(t0 + 2, 0);
            asm volatile("s_waitcnt vmcnt(8)" ::: "memory");   // t0+1 ready
        } else {
            asm volatile("s_waitcnt vmcnt(0)" ::: "memory");
        }
        asm volatile("s_barrier" ::: "memory");
        phase(65536, 0, true);
        if (t0 + 3 < 16) stageB(t0 + 3, 65536);
        phase(65536, 2, false); phase(65536, 4, false); phase(65536, 6, false);
        if (t0 + 3 < 16) {
            stageA(t0 + 3, 65536);
            asm volatile("s_waitcnt vmcnt(8)" ::: "memory");   // t0+2 ready
            asm volatile("s_barrier" ::: "memory");
        }
    }

    const bool isU = (col0 < 1024);
    const float* const bias = isU ? bu : bv;
    const float scl = isU ? KSCALE : 1.0f;
    bf16_t* const outp = isU ? uout : vout;
    const int cbase = col0 & 1023;

    float bv4[4];
    #pragma unroll
    for (int ni = 0; ni < 4; ++ni)
        bv4[ni] = bias[cbase + wn * 64 + ni * 16 + lr];
    #pragma unroll
    for (int mi = 0; mi < 8; ++mi)
        #pragma unroll
        for (int j = 0; j < 4; ++j) {
            const int grow = row0 + wm * 128 + mi * 16 + ko * 4 + j;
            #pragma unroll
            for (int ni = 0; ni < 4; ++ni) {
                const int gcol = cbase + wn * 64 + ni * 16 + lr;
                outp[(size_t)grow * CC + gcol] =
                    (bf16_t)((acc[mi][ni][j] + bv4[ni]) * scl);
            }
        }
}

// ---------------------------------------------------------------------------
// 128x128 2-phase out GEMM (T1 XCD swizzle, 2 blocks/CU):
//   out[8192,1024] fp32 = ybf @ WpT + bp.
// LDS 64 KB (2 bufs x [A 16K | B 16K]) -> 2 blocks/CU for TLP over vmcnt
// stalls. 8 waves 2M x 4N, wave output 64x32 (acc[4][2]). Per K-step:
// phase(mi 0-1, loads B) -> stageB(t+2) -> phase(mi 2-3) -> stageA(t+2) ->
// counted vmcnt(4) (drains t+1's 4 loads; t+2's stay in flight) -> barrier.
// ---------------------------------------------------------------------------
__global__ __launch_bounds__(512, 2) void mfma_gemm_out8_kernel(
    const bf16_t* __restrict__ A, const bf16_t* __restrict__ Bt,
    const float* __restrict__ bias, float* __restrict__ Cout)
{
    __shared__ __align__(16) char smem[65536];    // buf b at b*32768: A 16K, B 16K
    const int tid = threadIdx.x;
    const int wave = tid >> 6, lane = tid & 63;
    const int bid = (int)blockIdx.x;              // 0..511
    const int xcd = bid & 7, lid = bid >> 3;      // 64 blocks per XCD
    const int xq = (xcd & 1) * 4 + (lid & 3);     // col-block 0..7 (128 cols)
    const int yq = (xcd >> 1) * 16 + (lid >> 2);  // row-block 0..63 (128 rows)
    const int row0 = yq * 128, col0 = xq * 128;
    const int wm = wave >> 2, wn = wave & 3;      // 2 x 4 wave grid
    const int lr = lane & 15, ko = lane >> 4;
    const int koff = ((lane & 7) ^ (lane >> 3)) << 3;
    const int rsub = lane >> 3;

    int rdc[2];
    #pragma unroll
    for (int ks = 0; ks < 2; ++ks)
        rdc[ks] = ((((ks << 2) + ko) ^ (lr & 7)) << 4);
    const int arow = (wm << 6) + lr;              // + mi*16, mi 0..3
    const int brow = (wn << 5) + lr;              // + ni*16, ni 0..1

    f32x4 acc[4][2];
    #pragma unroll
    for (int i = 0; i < 4; ++i)
        #pragma unroll
        for (int j = 0; j < 2; ++j) acc[i][j] = (f32x4){0.f, 0.f, 0.f, 0.f};

    auto stageA = [&](int t, int bufbase) {       // 2 A loads per wave
        const int k0 = t << 6;
        const bf16_t* ag = A + (size_t)(row0 + wave * 16 + rsub) * CC + k0 + koff;
        char* da = smem + bufbase + wave * 2048;
        GLDS16(ag, da);
        GLDS16(ag + 8 * CC, da + 1024);
    };
    auto stageB = [&](int t, int bufbase) {       // 2 B loads per wave
        const int k0 = t << 6;
        const bf16_t* bg = Bt + (size_t)(col0 + wave * 16 + rsub) * CC + k0 + koff;
        char* db = smem + bufbase + 16384 + wave * 2048;
        GLDS16(bg, db);
        GLDS16(bg + 8 * CC, db + 1024);
    };

    bf16x8 bfr[2][2];
    auto phase = [&](int bufbase, int mi0, bool withB) {   // 8 MFMA
        const char* sA = smem + bufbase;
        const char* sB = smem + bufbase + 16384;
        if (withB) {
            #pragma unroll
            for (int ni = 0; ni < 2; ++ni)
                #pragma unroll
                for (int ks = 0; ks < 2; ++ks)
                    bfr[ni][ks] = *reinterpret_cast<const bf16x8*>(
                        sB + (brow + ni * 16) * 128 + rdc[ks]);
        }
        bf16x8 af[2][2];
        #pragma unroll
        for (int m2 = 0; m2 < 2; ++m2)
            #pragma unroll
            for (int ks = 0; ks < 2; ++ks)
                af[m2][ks] = *reinterpret_cast<const bf16x8*>(
                    sA + (arow + (mi0 + m2) * 16) * 128 + rdc[ks]);
        __builtin_amdgcn_s_setprio(1);
        #pragma unroll
        for (int m2 = 0; m2 < 2; ++m2)
            #pragma unroll
            for (int ni = 0; ni < 2; ++ni)
                #pragma unroll
                for (int ks = 0; ks < 2; ++ks)
                    acc[mi0 + m2][ni] = __builtin_amdgcn_mfma_f32_16x16x32_bf16(
                        af[m2][ks], bfr[ni][ks], acc[mi0 + m2][ni], 0, 0, 0);
        __builtin_amdgcn_s_setprio(0);
        asm volatile("s_barrier" ::: "memory");
    };

    // prologue: tiles 0 (buf0) and 1 (buf1); oldest 4 = tile0's loads
    stageA(0, 0);     stageB(0, 0);
    stageA(1, 32768); stageB(1, 32768);
    asm volatile("s_waitcnt vmcnt(4)" ::: "memory");
    asm volatile("s_barrier" ::: "memory");

    for (int i = 0; i < 8; ++i) {
        const int t0 = 2 * i;
        // K-step t0 from buf0
        phase(0, 0, true);
        if (t0 + 2 < 16) stageB(t0 + 2, 0);          // B dead after ph1
        phase(0, 2, false);                           // A dead after ph2
        if (t0 + 2 < 16) {
            stageA(t0 + 2, 0);
            asm volatile("s_waitcnt vmcnt(4)" ::: "memory");   // t0+1 ready
        } else {
            asm volatile("s_waitcnt vmcnt(0)" ::: "memory");
        }
        asm volatile("s_barrier" ::: "memory");
        // K-step t0+1 from buf1
        phase(32768, 0, true);
        if (t0 + 3 < 16) stageB(t0 + 3, 32768);
        phase(32768, 2, false);
        if (t0 + 3 < 16) {
            stageA(t0 + 3, 32768);
            asm volatile("s_waitcnt vmcnt(4)" ::: "memory");   // t0+2 ready
            asm volatile("s_barrier" ::: "memory");
        }
    }

    float bv2[2];
    #pragma unroll
    for (int ni = 0; ni < 2; ++ni)
        bv2[ni] = bias[col0 + wn * 32 + ni * 16 + lr];
    #pragma unroll
    for (int mi = 0; mi < 4; ++mi)
        #pragma unroll
        for (int j = 0; j < 4; ++j) {
            const int grow = row0 + wm * 64 + mi * 16 + ko * 4 + j;
            #pragma unroll
            for (int ni = 0; ni < 2; ++ni) {
                const int gcol = col0 + wn * 32 + ni * 16 + lr;
                Cout[(size_t)grow * CC + gcol] = acc[mi][ni][j] + bv2[ni];
            }
        }
}

// ---------------------------------------------------------------------------
// MFMA gated transform, transposed output -> vbT [B*H][64][TT] (kappa cols).
// ---------------------------------------------------------------------------
__global__ __launch_bounds__(256) void gate_mfma_kernel(
    const bf16_t* __restrict__ vp,
    const bf16_t* __restrict__ W1T, const bf16_t* __restrict__ W2T,
    const float* __restrict__ b1, const float* __restrict__ b2,
    bf16_t* __restrict__ vbT)
{
    __shared__ __align__(16) bf16_t Vs[64][64];
    const int tid = threadIdx.x, wave = tid >> 6, lane = tid & 63;
    const int t0 = blockIdx.x * 64;
    const int h = blockIdx.y;
    const int lr = lane & 15, ko = lane >> 4;
    const int koff = ((lane & 7) ^ (lane >> 3)) << 3;
    const int rsub = lane >> 3;

    #pragma unroll
    for (int i = 0; i < 2; ++i) {
        const int rb = (wave * 2 + i) * 8;
        GLDS16(vp + (size_t)(t0 + rb + rsub) * CC + h * 64 + koff,
               (char*)&Vs[rb][0]);
    }
    asm volatile("s_waitcnt vmcnt(0)" ::: "memory");
    __syncthreads();

    bf16x8 w1f[4][2], w2f[4][2];
    #pragma unroll
    for (int ni = 0; ni < 4; ++ni)
        #pragma unroll
        for (int kc = 0; kc < 2; ++kc) {
            w1f[ni][kc] = *reinterpret_cast<const bf16x8*>(
                &W1T[(ni * 16 + lr) * 64 + kc * 32 + ko * 8]);
            w2f[ni][kc] = *reinterpret_cast<const bf16x8*>(
                &W2T[(ni * 16 + lr) * 64 + kc * 32 + ko * 8]);
        }
    const int trow = wave * 16 + lr;
    bf16x8 vf[2];
    #pragma unroll
    for (int kc = 0; kc < 2; ++kc)
        vf[kc] = *reinterpret_cast<const bf16x8*>(
            (char*)Vs + trow * 128 + ((((kc << 2) + ko) ^ (trow & 7)) << 4));

    f32x4 Aacc[4], Gacc[4];
    #pragma unroll
    for (int ni = 0; ni < 4; ++ni) {
        Aacc[ni] = (f32x4){0.f, 0.f, 0.f, 0.f};
        Gacc[ni] = (f32x4){0.f, 0.f, 0.f, 0.f};
    }
    #pragma unroll
    for (int ni = 0; ni < 4; ++ni)
        #pragma unroll
        for (int kc = 0; kc < 2; ++kc) {
            Aacc[ni] = __builtin_amdgcn_mfma_f32_16x16x32_bf16(
                w1f[ni][kc], vf[kc], Aacc[ni], 0, 0, 0);
            Gacc[ni] = __builtin_amdgcn_mfma_f32_16x16x32_bf16(
                w2f[ni][kc], vf[kc], Gacc[ni], 0, 0, 0);
        }

    const int bidx = t0 >> 11;
    const int q2 = (lr >> 2) & 3;
    const int lrk = lr + (q2 == 1 ? 4 : (q2 == 2 ? -4 : 0));
    const int tb = (t0 & 2047) + wave * 16 + lrk;
    const size_t obase = (size_t)(bidx * HH + h) * HS * TT;
    #pragma unroll
    for (int ni = 0; ni < 4; ++ni)
        #pragma unroll
        for (int j = 0; j < 4; ++j) {
            const int d = ni * 16 + ko * 4 + j;
            const float vterm = (float)*(const bf16_t*)(
                (const char*)Vs + trow * 128 +
                ((((d >> 3) ^ (trow & 7)) << 4) + (d & 7) * 2));
            const float a = Aacc[ni][j] + b1[d];
            const float g = Gacc[ni][j] + b2[d];
            const float val = (vterm + a) * (1.f / (1.f + EXP2R(-g * LOG2E)));
            vbT[obase + (size_t)d * TT + tb] = (bf16_t)val;
        }
}

// ---------------------------------------------------------------------------
// MFMA flash attention v17: 8 waves (512 thr) x 32 q = 256-row q-blocks,
// KVBLK=128 staging shared by 8 waves, 2 blocks/CU -> 4 waves/SIMD.
// Static balanced mapping; counted vmcnt(4); raw barriers; no-max softmax
// (EXP2R); lane-local P; kappa-staged V^T; 32x32 swapped MFMA; setprio.
// ---------------------------------------------------------------------------
__global__ __launch_bounds__(512) void attn_mfma17_kernel(
    const bf16_t* __restrict__ ubf, const bf16_t* __restrict__ xbf,
    const bf16_t* __restrict__ vbT, bf16_t* __restrict__ ybf)
{
    __shared__ __align__(16) char KV[2 * 32768];   // buf b at b*32768: K 16K, V 16K

    const int tid = threadIdx.x, wave = tid >> 6, lane = tid & 63;
    const int l31 = lane & 31, hi = lane >> 5;
    const int koff = ((lane & 7) ^ (lane >> 3)) << 3;   // K staging inverse swz
    const int rsub = lane >> 3;

    // static balanced work mapping (18 trips/CU, heavy first)
    const int w = (int)blockIdx.x;          // 0..511
    const int s = w >> 8;                   // start order 0/1
    const int m = (w >> 6) & 3;
    const int qg = s ? m : 7 - m;           // pairs {m, 7-m}
    const int h = w & 15, b = (w >> 4) & 3;

    int lak[4], lav[4];
    #pragma unroll
    for (int cc = 0; cc < 4; ++cc) {
        const int xr = ((2 * cc + hi) ^ (l31 & 7)) << 4;
        lak[cc] = l31 * 128 + xr;
        lav[cc] = l31 * 256 + xr;
    }
    const int voffA = (((lane & 15) ^ (lane >> 4)) << 3);
    const int voffB = (((lane & 15) ^ ((lane >> 4) + 4)) << 3);

    f32x16 zero16;
    #pragma unroll
    for (int r = 0; r < 16; ++r) zero16[r] = 0.f;

    const int q0w = qg * 256 + wave * 32;
    const size_t rbase = (size_t)b * TT;
    const int hcol = h * 64;
    const size_t hVT = (size_t)(b * HH + h) * HS * TT;

    bf16x8 qf[4];
    #pragma unroll
    for (int dk = 0; dk < 4; ++dk)
        qf[dk] = *reinterpret_cast<const bf16x8*>(
            &ubf[(rbase + q0w + l31) * CC + hcol + dk * 16 + hi * 8]);

    f32x16 O[2];
    #pragma unroll
    for (int dt = 0; dt < 2; ++dt)
        #pragma unroll
        for (int r = 0; r < 16; ++r) O[dt][r] = 0.f;
    float l_ = 0.f;

    const int myn64 = (q0w + 95) >> 6;      // 64-key tiles needed
    const int mx128 = 2 * qg + 2;           // 128-key trips (>= 2)

    const bf16_t* xsK = xbf + (rbase + wave * 16 + rsub) * CC + hcol + koff;
    const bf16_t* vsA = vbT + hVT + (size_t)(wave * 8 + (lane >> 4)) * TT + voffA;
    const bf16_t* vsB = vbT + hVT + (size_t)(wave * 8 + (lane >> 4)) * TT + voffB;

    auto stage = [&](int bufbase) {         // 4 GLDS16 calls per wave
        char* dK = KV + bufbase + wave * 2048;          // K rows wave*16..+16
        GLDS16(xsK,          dK);
        GLDS16(xsK + 8 * CC, dK + 1024);
        char* dV = KV + bufbase + 16384 + wave * 2048;  // V rows wave*8..+8
        GLDS16(vsA,          dV);
        GLDS16(vsB + 4 * TT, dV + 1024);
        xsK += 128 * CC; vsA += 128; vsB += 128;
    };

    auto compute_sub = [&](int bufbase, int ss, int j) {  // 64-key sub-tile
        const char* const base = KV + bufbase;
        f32x16 S[2];
        __builtin_amdgcn_s_setprio(1);
        #pragma unroll
        for (int kb = 0; kb < 2; ++kb) {
            f32x16 sv = __builtin_amdgcn_mfma_f32_32x32x16_bf16(
                *reinterpret_cast<const bf16x8*>(
                    base + ss * 8192 + kb * 4096 + lak[0]),
                qf[0], zero16, 0, 0, 0);
            #pragma unroll
            for (int dk = 1; dk < 4; ++dk)
                sv = __builtin_amdgcn_mfma_f32_32x32x16_bf16(
                    *reinterpret_cast<const bf16x8*>(
                        base + ss * 8192 + kb * 4096 + lak[dk]),
                    qf[dk], sv, 0, 0, 0);
            S[kb] = sv;
        }
        __builtin_amdgcn_s_setprio(0);

        if (j == myn64 - 1) {               // causal mask, diagonal tile only
            const int k0 = j * 64;
            const int q = q0w + l31;
            #pragma unroll
            for (int kb = 0; kb < 2; ++kb)
                #pragma unroll
                for (int r = 0; r < 16; ++r) {
                    const int key = k0 + kb * 32 + (r & 3) + 8 * (r >> 2) + 4 * hi;
                    if (key > q) S[kb][r] = -1e30f;
                }
        }

        unsigned pw[2][4][2];
        float ps0 = 0.f, ps1 = 0.f;
        #pragma unroll
        for (int kb = 0; kb < 2; ++kb)
            #pragma unroll
            for (int gq = 0; gq < 4; ++gq)
                #pragma unroll
                for (int jj = 0; jj < 2; ++jj) {
                    const float p0 = EXP2R(S[kb][4 * gq + 2 * jj + 0]);
                    const float p1 = EXP2R(S[kb][4 * gq + 2 * jj + 1]);
                    ps0 += p0; ps1 += p1;
                    bf16x2 t; t[0] = (bf16_t)p0; t[1] = (bf16_t)p1;
                    pw[kb][gq][jj] = __builtin_bit_cast(unsigned, t);
                }
        l_ += ps0 + ps1;

        bf16x8 pfr[2][2];
        #pragma unroll
        for (int kb = 0; kb < 2; ++kb)
            #pragma unroll
            for (int ks = 0; ks < 2; ++ks) {
                u32x4 fw = {pw[kb][2 * ks][0], pw[kb][2 * ks][1],
                            pw[kb][2 * ks + 1][0], pw[kb][2 * ks + 1][1]};
                pfr[kb][ks] = __builtin_bit_cast(bf16x8, fw);
            }

        __builtin_amdgcn_s_setprio(1);
        #pragma unroll
        for (int dt = 0; dt < 2; ++dt)
            #pragma unroll
            for (int kb = 0; kb < 2; ++kb)
                #pragma unroll
                for (int ks = 0; ks < 2; ++ks) {
                    const bf16x8 vt = *reinterpret_cast<const bf16x8*>(
                        base + 16384 + dt * 8192 + ss * 128 + lav[2 * kb + ks]);
                    O[dt] = __builtin_amdgcn_mfma_f32_32x32x16_bf16(
                        vt, pfr[kb][ks], O[dt], 0, 0, 0);
                }
        __builtin_amdgcn_s_setprio(0);
    };

    // prologue: stage trips 0 (buf0) and 1 (buf1; mx128 >= 2 always)
    stage(0);
    stage(32768);
    asm volatile("s_waitcnt vmcnt(4)" ::: "memory");   // qf + trip0 done
    asm volatile("s_barrier" ::: "memory");

    int boff = 0;
    for (int kt = 0; kt < mx128; ++kt) {
        const int j0 = 2 * kt;
        if (j0 < myn64)     compute_sub(boff, 0, j0);
        if (j0 + 1 < myn64) compute_sub(boff, 1, j0 + 1);
        asm volatile("s_barrier" ::: "memory");   // all waves done with buf
        if (kt + 2 < mx128) {
            stage(boff);                           // trip kt+2 -> same buf
            asm volatile("s_waitcnt vmcnt(4)" ::: "memory");  // kt+1 ready
        } else {
            asm volatile("s_waitcnt vmcnt(0)" ::: "memory");
        }
        asm volatile("s_barrier" ::: "memory");
        boff ^= 32768;
    }

    // epilogue: lane = query q0w+l31; O reg r -> d = dt*32+(r&3)+8*(r>>2)+4*hi
    const float lrow = l_ + __shfl_xor(l_, 32);
    const float inv = 1.f / lrow;
    const size_t grow = rbase + q0w + l31;
    #pragma unroll
    for (int dt = 0; dt < 2; ++dt)
        #pragma unroll
        for (int g2 = 0; g2 < 4; ++g2) {
            bf16x4v o4;
            #pragma unroll
            for (int j = 0; j < 4; ++j) o4[j] = (bf16_t)(O[dt][4 * g2 + j] * inv);
            const int d0 = dt * 32 + 8 * g2 + 4 * hi;
            *reinterpret_cast<bf16x4v*>(&ybf[grow * CC + hcol + d0]) = o4;
        }
}

// ---------------------------------------------------------------------------
extern "C" void kernel_launch(void* const* d_in, const int* in_sizes, int n_in,
                              void* d_out, int out_size, void* d_ws, size_t ws_size,
                              hipStream_t stream)
{
    (void)in_sizes; (void)n_in; (void)out_size; (void)ws_size;
    const float* x  = (const float*)d_in[0];
    const float* Wu = (const float*)d_in[1];
    const float* bu = (const float*)d_in[2];
    const float* Wv = (const float*)d_in[3];
    const float* bv = (const float*)d_in[4];
    const float* W1 = (const float*)d_in[5];
    const float* b1 = (const float*)d_in[6];
    const float* W2 = (const float*)d_in[7];
    const float* b2 = (const float*)d_in[8];
    const float* Wp = (const float*)d_in[9];
    const float* bp = (const float*)d_in[10];
    float* out = (float*)d_out;

    const size_t NE = (size_t)ROWS * CC;
    bf16_t* xbf = (bf16_t*)d_ws;                    // 16 MB
    bf16_t* ubf = xbf + NE;                         // 16 MB
    bf16_t* vp  = ubf + NE;                         // 16 MB
    bf16_t* vbT = vp  + NE;                         // 16 MB
    bf16_t* WuT = vbT + NE;                         // 2 MB  -- contiguous with
    bf16_t* WvT = WuT + (size_t)CC * CC;            // 2 MB  -- WuT: [2048][1024]
    bf16_t* WpT = WvT + (size_t)CC * CC;            // 2 MB
    bf16_t* W1T = WpT + (size_t)CC * CC;            // 8 KB
    bf16_t* W2T = W1T + (size_t)HS * HS;            // 8 KB
    bf16_t* ybf = vp;                               // alias: vp dead after gate

    prep_kernel<<<4865, 256, 0, stream>>>(
        x, xbf, Wu, Wv, Wp, WuT, WvT, WpT, W1, W2, W1T, W2T);

    mfma_gemm_uv8_kernel<<<256, 512, 0, stream>>>(
        xbf, WuT, bu, bv, ubf, vp);
    gate_mfma_kernel<<<dim3(ROWS / 64, HH), 256, 0, stream>>>(
        vp, W1T, W2T, b1, b2, vbT);
    attn_mfma17_kernel<<<512, 512, 0, stream>>>(ubf, xbf, vbT, ybf);
    mfma_gemm_out8_kernel<<<512, 512, 0, stream>>>(ybf, WpT, bp, out);
}